// Round 11
// baseline (260.482 us; speedup 1.0000x reference)
//
#include <hip/hip_runtime.h>
#include <hip/hip_bf16.h>

typedef __attribute__((ext_vector_type(8))) short short8;
typedef __attribute__((ext_vector_type(4))) float f32x4;

#define O 144
#define NB 32
#define GT 256
#define NPAIRS 10440   // 144*145/2
#define TP 128         // pairs per rn_main block (R6 best)
#define NT 82          // ceil(10440/128)
#define GRID (NB*NT)   // 2624 = 8 * 328
#define CHUNK 328      // per-XCD chunk (= exactly 4 batches)

// workspace byte offsets
#define WS_WT   0u          // 3 * 256*256 bf16, k-tiled panel layout (R6 mapping)
#define WS_U    393216u     // 32*144*256 bf16 (u + wq + gb0 folded)
#define WS_V    2752512u    // 32*144*256 bf16
#define WS_REL  5144576u    // 32*256 f32
#define WS_CNT  5177344u    // 32 ints

__device__ __forceinline__ unsigned short f2bf(float f){
  unsigned int uu = __builtin_bit_cast(unsigned int, f);
  unsigned int lsb = (uu >> 16) & 1u;
  uu += 0x7fffu + lsb;               // round-to-nearest-even
  return (unsigned short)(uu >> 16);
}
// HW packed f32->bf16 (RNE), 2 elements in 1 instr
__device__ __forceinline__ unsigned int cvtpk(float lo, float hi){
  unsigned int r;
  asm("v_cvt_pk_bf16_f32 %0, %1, %2" : "=v"(r) : "v"(lo), "v"(hi));
  return r;
}

// ---- merged prep ----
// blocks [0,256): u/v build; blocks [256,1024): Wt panels (R6 mapping) + rel/cnt zero
__global__ void prep_all(const float* __restrict__ x, const float* __restrict__ q,
                         const float* __restrict__ gW0, const float* __restrict__ gb0,
                         const float* __restrict__ gW1, const float* __restrict__ gW2,
                         const float* __restrict__ gW3,
                         unsigned short* __restrict__ u, unsigned short* __restrict__ v,
                         unsigned short* __restrict__ WtP, float* __restrict__ rel,
                         int* __restrict__ cnt){
  int blk = blockIdx.x, t = threadIdx.x;
  if (blk < 256){
    __shared__ float xs[24][18];
    __shared__ float qs[128];
    int n = blk >> 3, oq = blk & 7;
    int o0 = oq * 18;
    for (int i = t; i < 432; i += 256){
      int c = i / 18, oo = i - c*18;
      xs[c][oo] = x[(n*24 + c)*144 + o0 + oo];
    }
    if (t < 128) qs[t] = q[n*128 + t];
    __syncthreads();
    float wq = gb0[t];
    for (int d = 0; d < 128; d++) wq += qs[d] * gW0[(52 + d)*GT + t];
    float wc[52];
    #pragma unroll
    for (int c = 0; c < 52; c++) wc[c] = gW0[c*GT + t];
    for (int oo = 0; oo < 18; oo++){
      int o = o0 + oo;
      float xc = -1.f + 2.f * (float)(o / 12) / 11.f;
      float yc = -1.f + 2.f * (float)(o % 12) / 11.f;
      float su = wq + xc*wc[24] + yc*wc[25];
      float sv =      xc*wc[50] + yc*wc[51];
      #pragma unroll
      for (int c = 0; c < 24; c++){ float f = xs[c][oo]; su += f*wc[c]; sv += f*wc[26+c]; }
      u[(size_t)(n*O + o)*GT + t] = f2bf(su);
      v[(size_t)(n*O + o)*GT + t] = f2bf(sv);
    }
  } else {
    int b2 = blk - 256;                // 0..767
    int li = b2 >> 8, e = b2 & 255;
    int k = t;
    const float* W = (li == 0) ? gW1 : (li == 1) ? gW2 : gW3;
    // panel: [li][ (e>>4)*4096 + (k>>5)*512 + (e&15)*32 + ((k>>3)&3)*8 + (k&7) ]
    int et = e >> 4, r = e & 15;
    int kk = k >> 5, g = (k >> 3) & 3, d = k & 7;
    WtP[li*65536 + et*4096 + kk*512 + r*32 + g*8 + d] = f2bf(W[k*GT + e]);
    if (b2 < NB) rel[b2*GT + t] = 0.f;
    if (b2 == 0 && t < NB) cnt[t] = 0;
  }
}

// ---- main fused kernel: 16x16x32 MFMA, A ping-pong + B double-buffer ----
// LDS h layout: h[row][col] bf16 at byte  row*512 + ((col*2) ^ ((row&7)<<4))
__global__ __launch_bounds__(256, 2) void rn_main(
    const unsigned short* __restrict__ u, const unsigned short* __restrict__ v,
    const unsigned short* __restrict__ WtP,
    const float* __restrict__ gb1, const float* __restrict__ gb2,
    const float* __restrict__ gb3, float* __restrict__ rel, int* __restrict__ cnt,
    const float* __restrict__ fW0, const float* __restrict__ fb0,
    const float* __restrict__ fW1, const float* __restrict__ fb1,
    const float* __restrict__ fW2, const float* __restrict__ fb2,
    float* __restrict__ out)
{
  __shared__ short8 hbuf[4096];        // 128 rows x 512B = 64 KiB
  char* lds = (char*)hbuf;

  const int tid  = threadIdx.x;
  const int lane = tid & 63;
  const int wav  = tid >> 6;           // owns feats [wav*64, +64)
  int lg = (blockIdx.x & 7)*CHUNK + (blockIdx.x >> 3);   // bijective XCD swizzle
  const int n    = lg / NT;
  const int tile = lg - n*NT;
  const int tbase = tile * TP;
  const int l15 = lane & 15, l4 = lane >> 4;

  // A-prefetch: phase p = L*8+kk in [0,24); 2-set ping-pong by phase parity
  const unsigned short* wb = WtP + wav*16384 + l15*32 + l4*8;
  short8 aP0,aP1,aP2,aP3, aQ0,aQ1,aQ2,aQ3;
#define LA(s0,s1,s2,s3,p_) { const unsigned short* _wp = wb + ((p_) >> 3)*65536 + ((p_) & 7)*512; \
    s0 = *(const short8*)(_wp);        s1 = *(const short8*)(_wp + 4096); \
    s2 = *(const short8*)(_wp + 8192); s3 = *(const short8*)(_wp + 12288); }
  LA(aP0,aP1,aP2,aP3, 0)
  LA(aQ0,aQ1,aQ2,aQ3, 1)

  // ---- stage h0 = relu(u'[n,b] + v[n,a]); 2 lanes per row, rows 0..127 ----
  {
    int row = wav*32 + (lane >> 1);
    int pt  = tbase + row;
    bool valid = pt < NPAIRS;
    int pa = 0, pb = 0;
    if (valid){
      pa = (int)((sqrtf(8.f*(float)pt + 1.f) - 1.f) * 0.5f);
      while ((pa + 1)*(pa + 2)/2 <= pt) pa++;
      while (pa*(pa + 1)/2 > pt) pa--;
      pb = pt - pa*(pa + 1)/2;
    }
    const uint4* up4 = (const uint4*)(u + (size_t)(n*O + pb)*GT);
    const uint4* vp4 = (const uint4*)(v + (size_t)(n*O + pa)*GT);
    int half = lane & 1;
    int sbase = row*512 + half*256;
    int ts = ((lane >> 1) & 7) << 4;   // (row&7)<<4
    #pragma unroll
    for (int cc = 0; cc < 16; cc++){
      uint4 hv;
      if (valid){
        uint4 uu = up4[half*16 + cc];
        uint4 vv = vp4[half*16 + cc];
        #pragma unroll
        for (int j = 0; j < 4; j++){
          unsigned int ud = (&uu.x)[j], vd = (&vv.x)[j];
          float lo = __builtin_bit_cast(float, ud << 16) + __builtin_bit_cast(float, vd << 16);
          float hi = __builtin_bit_cast(float, ud & 0xffff0000u) + __builtin_bit_cast(float, vd & 0xffff0000u);
          (&hv.x)[j] = cvtpk(fmaxf(lo, 0.f), fmaxf(hi, 0.f));
        }
      } else {
        hv = (uint4){0u, 0u, 0u, 0u};
      }
      *(uint4*)(lds + sbase + ((cc*16) ^ ts)) = hv;
    }
  }
  __syncthreads();

  const bool fullvalid = (tbase + TP <= NPAIRS);
  // B-read bases: true byte = jp*8192 + l15*512 + ((kk*64 + l4*16) ^ ((l15&7)<<4))
  const int swz01 = (l15 & 3) << 4;
  const int swz2  = (l15 & 4) << 4;          // 0 or 64
  const int rbE = l15*512 + ((l4*16) ^ swz01) + swz2;   // even kk
  const int rbO = l15*512 + ((l4*16) ^ swz01) - swz2;   // odd kk
  const int ebase = l15*512 + wav*128 + ((l4*8) ^ ((l15 & 1) << 4)) + ((l15 & 6) << 4);
  f32x4 acc[4][8];
  short8 b0[8], b1[8];

#define LOADB(dst_, kk_) { const int rb_ = ((kk_) & 1) ? rbO : rbE; \
    _Pragma("unroll") \
    for (int jp = 0; jp < 8; jp++) dst_[jp] = *(short8*)(lds + rb_ + jp*8192 + (kk_)*64); }

#define MFMAB(bb_, s0,s1,s2,s3) { \
    __builtin_amdgcn_s_setprio(1); \
    _Pragma("unroll") \
    for (int jp = 0; jp < 8; jp++){ \
      acc[0][jp] = __builtin_amdgcn_mfma_f32_16x16x32_bf16(s0, bb_[jp], acc[0][jp], 0, 0, 0); \
      acc[1][jp] = __builtin_amdgcn_mfma_f32_16x16x32_bf16(s1, bb_[jp], acc[1][jp], 0, 0, 0); \
      acc[2][jp] = __builtin_amdgcn_mfma_f32_16x16x32_bf16(s2, bb_[jp], acc[2][jp], 0, 0, 0); \
      acc[3][jp] = __builtin_amdgcn_mfma_f32_16x16x32_bf16(s3, bb_[jp], acc[3][jp], 0, 0, 0); } \
    __builtin_amdgcn_s_setprio(0); }

  #pragma unroll
  for (int L = 0; L < 3; L++){
    const float* gb = (L == 0) ? gb1 : (L == 1) ? gb2 : gb3;

    // init accumulators with bias (feature e = wav*64 + ie*16 + l4*4 + j)
    #pragma unroll
    for (int ie = 0; ie < 4; ie++){
      f32x4 bbv = *(const f32x4*)(gb + wav*64 + ie*16 + l4*4);
      #pragma unroll
      for (int jp = 0; jp < 8; jp++) acc[ie][jp] = bbv;
    }

    LOADB(b0, 0);                      // first B of this layer (post-barrier)
    #pragma unroll
    for (int kk = 0; kk < 8; kk++){
      const int p  = L*8 + kk;
      const int pn = (p + 2 > 23) ? 23 : p + 2;
      // copy current A set to locals, then reload that set for p+2 (issue early)
      short8 c0,c1,c2,c3;
      if (p & 1){ c0=aQ0; c1=aQ1; c2=aQ2; c3=aQ3; }
      else      { c0=aP0; c1=aP1; c2=aP2; c3=aP3; }
      // prefetch next kk's B before this kk's MFMA burst (hide lgkm under MFMA)
      if (kk < 7){ if (kk & 1) { LOADB(b0, kk + 1) } else { LOADB(b1, kk + 1) } }
      if (p & 1){ LA(aQ0,aQ1,aQ2,aQ3, pn) } else { LA(aP0,aP1,aP2,aP3, pn) }
      if (kk & 1){ MFMAB(b1, c0,c1,c2,c3) } else { MFMAB(b0, c0,c1,c2,c3) }
    }

    if (L < 2){
      __syncthreads();                 // all waves done reading h_in
      #pragma unroll
      for (int ie = 0; ie < 4; ie++){
        int ea = ebase ^ (ie*32);
        #pragma unroll
        for (int jp = 0; jp < 8; jp++){
          uint2 pk;
          pk.x = cvtpk(fmaxf(acc[ie][jp][0], 0.f), fmaxf(acc[ie][jp][1], 0.f));
          pk.y = cvtpk(fmaxf(acc[ie][jp][2], 0.f), fmaxf(acc[ie][jp][3], 0.f));
          *(uint2*)(lds + ea + jp*8192) = pk;
        }
      }
      __syncthreads();                 // h_out visible to all waves
    } else {
      // layer 3: relu, mask tail pairs, sum over pairs -> atomic into rel
      #pragma unroll
      for (int ie = 0; ie < 4; ie++){
        int e0 = wav*64 + ie*16 + l4*4;
        f32x4 s = {0.f, 0.f, 0.f, 0.f};
        #pragma unroll
        for (int jp = 0; jp < 8; jp++){
          bool pv = fullvalid || (tbase + jp*16 + l15 < NPAIRS);
          #pragma unroll
          for (int j = 0; j < 4; j++){
            float hvv = fmaxf(acc[ie][jp][j], 0.f);
            s[j] += pv ? hvv : 0.f;
          }
        }
        #pragma unroll
        for (int st = 1; st < 16; st <<= 1){
          #pragma unroll
          for (int j = 0; j < 4; j++)
            s[j] += __shfl_xor(s[j], st);
        }
        if (l15 == 0){
          #pragma unroll
          for (int j = 0; j < 4; j++)
            atomicAdd(&rel[n*GT + e0 + j], s[j]);
        }
      }
    }
  }
#undef LA
#undef LOADB
#undef MFMAB

  // ---- completion count; last block of batch n runs f_phi ----
  __syncthreads();
  if (tid == 0) ((int*)lds)[0] = atomicAdd(&cnt[n], 1);
  __syncthreads();
  int done = ((int*)lds)[0];
  __syncthreads();                     // everyone consumed flag before LDS reuse
  if (done == NT - 1){
    float rv = atomicAdd(&rel[n*GT + tid], 0.f);   // coherent read across XCDs
    float* hsm = (float*)lds;
    float* ysm = hsm + 256;
    int t = tid;
    hsm[t] = rv;
    __syncthreads();
    float s = fb0[t];
    for (int k = 0; k < 256; k++) s += hsm[k] * fW0[k*GT + t];
    ysm[t] = fmaxf(s, 0.f);
    __syncthreads();
    s = fb1[t];
    for (int k = 0; k < 256; k++) s += ysm[k] * fW1[k*GT + t];
    __syncthreads();
    hsm[t] = fmaxf(s, 0.f);
    __syncthreads();
    if (t < 28){
      s = fb2[t];
      for (int k = 0; k < 256; k++) s += hsm[k] * fW2[k*28 + t];
      out[n*28 + t] = s;
    }
  }
}

extern "C" void kernel_launch(void* const* d_in, const int* in_sizes, int n_in,
                              void* d_out, int out_size, void* d_ws, size_t ws_size,
                              hipStream_t stream){
  (void)in_sizes; (void)n_in; (void)out_size; (void)ws_size;
  const float* x   = (const float*)d_in[0];
  const float* q   = (const float*)d_in[1];
  const float* gW0 = (const float*)d_in[2];
  const float* gb0 = (const float*)d_in[3];
  const float* gW1 = (const float*)d_in[4];
  const float* gb1 = (const float*)d_in[5];
  const float* gW2 = (const float*)d_in[6];
  const float* gb2 = (const float*)d_in[7];
  const float* gW3 = (const float*)d_in[8];
  const float* gb3 = (const float*)d_in[9];
  const float* fW0 = (const float*)d_in[10];
  const float* fb0 = (const float*)d_in[11];
  const float* fW1 = (const float*)d_in[12];
  const float* fb1 = (const float*)d_in[13];
  const float* fW2 = (const float*)d_in[14];
  const float* fb2 = (const float*)d_in[15];

  char* ws = (char*)d_ws;
  unsigned short* WtP = (unsigned short*)(ws + WS_WT);
  unsigned short* u   = (unsigned short*)(ws + WS_U);
  unsigned short* v   = (unsigned short*)(ws + WS_V);
  float* rel = (float*)(ws + WS_REL);
  int*   cnt = (int*)(ws + WS_CNT);
  float* out = (float*)d_out;

  hipLaunchKernelGGL(prep_all, dim3(1024), dim3(256), 0, stream,
                     x, q, gW0, gb0, gW1, gW2, gW3, u, v, WtP, rel, cnt);
  hipLaunchKernelGGL(rn_main, dim3(GRID), dim3(256), 0, stream,
                     u, v, WtP, gb1, gb2, gb3, rel, cnt,
                     fW0, fb0, fW1, fb1, fW2, fb2, out);
}